// Round 3
// baseline (139.165 us; speedup 1.0000x reference)
//
#include <hip/hip_runtime.h>
#include <math.h>

constexpr int E_EDGES = 4194304;
constexpr float EPS_W = 1e-8f;

typedef int   iv4 __attribute__((ext_vector_type(4)));
typedef float fv4 __attribute__((ext_vector_type(4)));

__global__ __launch_bounds__(256, 4) void ba_kernel(
    const float* __restrict__ poses,       // 2048*7
    const float* __restrict__ pc_rt,       // 524288 x (r,theta)
    const float* __restrict__ elev,        // 524288
    const float* __restrict__ scale,       // 2
    const fv4*   __restrict__ baseline4,   // 2 edges per fv4
    const fv4*   __restrict__ weights4,    // 2 edges per fv4
    const iv4*   __restrict__ patch_idx4,
    const iv4*   __restrict__ inv_idx4,
    const iv4*   __restrict__ src_idx4,
    const iv4*   __restrict__ tgt_idx4,
    fv4*         __restrict__ out4)        // 2 edges per fv4
{
    const float sx = scale[0];
    const float sy = scale[1];
    const int t = blockIdx.x * blockDim.x + threadIdx.x;  // one thread = 4 edges

    // ---- streamed, read-once: nontemporal vector loads ----
    const iv4 pi = __builtin_nontemporal_load(patch_idx4 + t);
    const iv4 ii = __builtin_nontemporal_load(inv_idx4 + t);
    const iv4 si = __builtin_nontemporal_load(src_idx4 + t);
    const iv4 ti = __builtin_nontemporal_load(tgt_idx4 + t);

    const fv4 bl01 = __builtin_nontemporal_load(baseline4 + 2 * t);
    const fv4 bl23 = __builtin_nontemporal_load(baseline4 + 2 * t + 1);
    const fv4 w01  = __builtin_nontemporal_load(weights4 + 2 * t);
    const fv4 w23  = __builtin_nontemporal_load(weights4 + 2 * t + 1);

    // ---- issue ALL gathers before any compute (ILP) ----
    float pcr[4], pct[4];
    float ph[4];
    float S[4][7], T[4][7];
#pragma unroll
    for (int i = 0; i < 4; ++i) {
        const int p = ((const int*)&pi)[i];
        const int v = ((const int*)&ii)[i];
        const int s = ((const int*)&si)[i];
        const int g = ((const int*)&ti)[i];
        pcr[i] = pc_rt[2 * (size_t)p];
        pct[i] = pc_rt[2 * (size_t)p + 1];
        ph[i]  = elev[v];
        const float* Pp = poses + (size_t)s * 7;
        const float* Tp = poses + (size_t)g * 7;
#pragma unroll
        for (int j = 0; j < 7; ++j) { S[i][j] = Pp[j]; T[i][j] = Tp[j]; }
    }

    // ---- compute ----
    float rx[4], ry[4];
#pragma unroll
    for (int i = 0; i < 4; ++i) {
        float sphi, cphi, sth, cth;
        __sincosf(ph[i],  &sphi, &cphi);
        __sincosf(pct[i], &sth,  &cth);

        const float rcp = pcr[i] * cphi;
        const float lx = rcp * cth;
        const float ly = rcp * sth;
        const float lz = pcr[i] * sphi;

        const float qx = S[i][3], qy = S[i][4], qz = S[i][5], qw = S[i][6];
        const float t0 = 2.0f * (qy * lz - qz * ly);
        const float t1 = 2.0f * (qz * lx - qx * lz);
        const float t2 = 2.0f * (qx * ly - qy * lx);
        const float gx = lx + qw * t0 + (qy * t2 - qz * t1) + S[i][0];
        const float gy = ly + qw * t1 + (qz * t0 - qx * t2) + S[i][1];
        const float gz = lz + qw * t2 + (qx * t1 - qy * t0) + S[i][2];

        const float dx = gx - T[i][0];
        const float dy = gy - T[i][1];
        const float dz = gz - T[i][2];
        const float uqx = -T[i][3], uqy = -T[i][4], uqz = -T[i][5], uqw = T[i][6];

        const float u0 = 2.0f * (uqy * dz - uqz * dy);
        const float u1 = 2.0f * (uqz * dx - uqx * dz);
        const float u2 = 2.0f * (uqx * dy - uqy * dx);
        const float ox = dx + uqw * u0 + (uqy * u2 - uqz * u1);
        const float oy = dy + uqw * u1 + (uqz * u0 - uqx * u2);
        const float oz = dz + uqw * u2 + (uqx * u1 - uqy * u0);

        rx[i] = sqrtf(ox * ox + oy * oy + oz * oz) * sx;
        ry[i] = atan2f(oy, ox) * sy;
    }

    // ---- weighted residual + store ----
    fv4 o01, o23;
    o01.x = (rx[0] - bl01.x) * sqrtf(w01.x + EPS_W);
    o01.y = (ry[0] - bl01.y) * sqrtf(w01.y + EPS_W);
    o01.z = (rx[1] - bl01.z) * sqrtf(w01.z + EPS_W);
    o01.w = (ry[1] - bl01.w) * sqrtf(w01.w + EPS_W);
    o23.x = (rx[2] - bl23.x) * sqrtf(w23.x + EPS_W);
    o23.y = (ry[2] - bl23.y) * sqrtf(w23.y + EPS_W);
    o23.z = (rx[3] - bl23.z) * sqrtf(w23.z + EPS_W);
    o23.w = (ry[3] - bl23.w) * sqrtf(w23.w + EPS_W);

    __builtin_nontemporal_store(o01, out4 + 2 * t);
    __builtin_nontemporal_store(o23, out4 + 2 * t + 1);
}

extern "C" void kernel_launch(void* const* d_in, const int* in_sizes, int n_in,
                              void* d_out, int out_size, void* d_ws, size_t ws_size,
                              hipStream_t stream) {
    const float* poses    = (const float*)d_in[0];
    const float* pc_rt    = (const float*)d_in[1];
    const float* elev     = (const float*)d_in[2];
    const float* scale    = (const float*)d_in[3];
    const fv4*   baseline = (const fv4*)d_in[4];
    const fv4*   weights4 = (const fv4*)d_in[5];
    const iv4*   patch_i  = (const iv4*)d_in[6];
    const iv4*   inv_i    = (const iv4*)d_in[7];
    const iv4*   src_i    = (const iv4*)d_in[8];
    const iv4*   tgt_i    = (const iv4*)d_in[9];
    fv4*         out      = (fv4*)d_out;

    const int threads = E_EDGES / 4;          // 1,048,576
    dim3 grid(threads / 256), block(256);     // 4096 blocks
    hipLaunchKernelGGL(ba_kernel, grid, block, 0, stream,
                       poses, pc_rt, elev, scale, baseline, weights4,
                       patch_i, inv_i, src_i, tgt_i, out);
}

// Round 4
// 92.727 us; speedup vs baseline: 1.5008x; 1.5008x over previous
//
#include <hip/hip_runtime.h>
#include <math.h>

constexpr int E_EDGES = 4194304;
constexpr int N_PATCH = 524288;
constexpr int N_POSES = 2048;
constexpr float EPS_W = 1e-8f;

typedef int   iv4 __attribute__((ext_vector_type(4)));
typedef float fv4 __attribute__((ext_vector_type(4)));
typedef float fv2 __attribute__((ext_vector_type(2)));

// ---- prep 1: fold r/theta/phi trig into a local_src float4 table ----
__global__ __launch_bounds__(256) void prep_patches(
    const fv2*  __restrict__ pc_rt,   // N_PATCH x (r,theta)
    const float* __restrict__ elev,   // N_PATCH
    fv4*        __restrict__ local4)  // N_PATCH x (lx,ly,lz,0)
{
    const int j = blockIdx.x * blockDim.x + threadIdx.x;
    if (j >= N_PATCH) return;
    const fv2 pc = pc_rt[j];
    const float phi = elev[j];
    float sphi, cphi, sth, cth;
    __sincosf(phi,  &sphi, &cphi);
    __sincosf(pc.y, &sth,  &cth);
    const float rcp = pc.x * cphi;
    fv4 o;
    o.x = rcp * cth;
    o.y = rcp * sth;
    o.z = pc.x * sphi;
    o.w = 0.0f;
    local4[j] = o;
}

// ---- prep 2: pad poses 7 -> 8 floats (2x dwordx4 gathers) ----
__global__ __launch_bounds__(256) void prep_poses(
    const float* __restrict__ poses, fv4* __restrict__ poses8)
{
    const int j = blockIdx.x * blockDim.x + threadIdx.x;
    if (j >= N_POSES) return;
    const float* p = poses + (size_t)j * 7;
    fv4 a, b;
    a.x = p[0]; a.y = p[1]; a.z = p[2]; a.w = p[3];   // px py pz qx
    b.x = p[4]; b.y = p[5]; b.z = p[6]; b.w = 0.0f;   // qy qz qw -
    poses8[2 * j]     = a;
    poses8[2 * j + 1] = b;
}

// ---- main: 4 edges/thread, 5 divergent loads/edge, no trig ----
__global__ __launch_bounds__(256, 4) void ba_main(
    const fv4*  __restrict__ poses8,
    const fv4*  __restrict__ local4,
    const float* __restrict__ scale,
    const fv4*  __restrict__ baseline4,
    const fv4*  __restrict__ weights4,
    const iv4*  __restrict__ patch_idx4,
    const iv4*  __restrict__ src_idx4,
    const iv4*  __restrict__ tgt_idx4,
    fv4*        __restrict__ out4)
{
    const int t = blockIdx.x * blockDim.x + threadIdx.x;

    const iv4 pi = __builtin_nontemporal_load(patch_idx4 + t);
    const iv4 si = __builtin_nontemporal_load(src_idx4 + t);
    const iv4 ti = __builtin_nontemporal_load(tgt_idx4 + t);

    const fv4 bl01 = __builtin_nontemporal_load(baseline4 + 2 * t);
    const fv4 bl23 = __builtin_nontemporal_load(baseline4 + 2 * t + 1);
    const fv4 w01  = __builtin_nontemporal_load(weights4 + 2 * t);
    const fv4 w23  = __builtin_nontemporal_load(weights4 + 2 * t + 1);

    // issue ALL gathers back-to-back (20 independent dwordx4)
    fv4 L[4], S0[4], S1[4], T0[4], T1[4];
#pragma unroll
    for (int i = 0; i < 4; ++i) {
        const int p = ((const int*)&pi)[i];
        const int s = ((const int*)&si)[i];
        const int g = ((const int*)&ti)[i];
        L[i]  = local4[p];
        S0[i] = poses8[2 * (size_t)s];
        S1[i] = poses8[2 * (size_t)s + 1];
        T0[i] = poses8[2 * (size_t)g];
        T1[i] = poses8[2 * (size_t)g + 1];
    }
    __builtin_amdgcn_sched_barrier(0);  // keep gathers hoisted: 20-deep MLP

    const float sx = scale[0];
    const float sy = scale[1];

    float rx[4], ry[4];
#pragma unroll
    for (int i = 0; i < 4; ++i) {
        const float lx = L[i].x, ly = L[i].y, lz = L[i].z;

        const float qx = S0[i].w, qy = S1[i].x, qz = S1[i].y, qw = S1[i].z;
        const float t0 = 2.0f * (qy * lz - qz * ly);
        const float t1 = 2.0f * (qz * lx - qx * lz);
        const float t2 = 2.0f * (qx * ly - qy * lx);
        const float gx = lx + qw * t0 + (qy * t2 - qz * t1) + S0[i].x;
        const float gy = ly + qw * t1 + (qz * t0 - qx * t2) + S0[i].y;
        const float gz = lz + qw * t2 + (qx * t1 - qy * t0) + S0[i].z;

        const float dx = gx - T0[i].x;
        const float dy = gy - T0[i].y;
        const float dz = gz - T0[i].z;
        const float uqx = -T0[i].w, uqy = -T1[i].x, uqz = -T1[i].y, uqw = T1[i].z;

        const float u0 = 2.0f * (uqy * dz - uqz * dy);
        const float u1 = 2.0f * (uqz * dx - uqx * dz);
        const float u2 = 2.0f * (uqx * dy - uqy * dx);
        const float ox = dx + uqw * u0 + (uqy * u2 - uqz * u1);
        const float oy = dy + uqw * u1 + (uqz * u0 - uqx * u2);
        const float oz = dz + uqw * u2 + (uqx * u1 - uqy * u0);

        rx[i] = sqrtf(ox * ox + oy * oy + oz * oz) * sx;
        ry[i] = atan2f(oy, ox) * sy;
    }

    fv4 o01, o23;
    o01.x = (rx[0] - bl01.x) * sqrtf(w01.x + EPS_W);
    o01.y = (ry[0] - bl01.y) * sqrtf(w01.y + EPS_W);
    o01.z = (rx[1] - bl01.z) * sqrtf(w01.z + EPS_W);
    o01.w = (ry[1] - bl01.w) * sqrtf(w01.w + EPS_W);
    o23.x = (rx[2] - bl23.x) * sqrtf(w23.x + EPS_W);
    o23.y = (ry[2] - bl23.y) * sqrtf(w23.y + EPS_W);
    o23.z = (rx[3] - bl23.z) * sqrtf(w23.z + EPS_W);
    o23.w = (ry[3] - bl23.w) * sqrtf(w23.w + EPS_W);

    __builtin_nontemporal_store(o01, out4 + 2 * t);
    __builtin_nontemporal_store(o23, out4 + 2 * t + 1);
}

// ---- fallback (round-3 proven kernel) if ws is too small ----
__global__ __launch_bounds__(256, 4) void ba_fallback(
    const float* __restrict__ poses,
    const float* __restrict__ pc_rt,
    const float* __restrict__ elev,
    const float* __restrict__ scale,
    const fv4*   __restrict__ baseline4,
    const fv4*   __restrict__ weights4,
    const iv4*   __restrict__ patch_idx4,
    const iv4*   __restrict__ inv_idx4,
    const iv4*   __restrict__ src_idx4,
    const iv4*   __restrict__ tgt_idx4,
    fv4*         __restrict__ out4)
{
    const float sx = scale[0];
    const float sy = scale[1];
    const int t = blockIdx.x * blockDim.x + threadIdx.x;

    const iv4 pi = __builtin_nontemporal_load(patch_idx4 + t);
    const iv4 ii = __builtin_nontemporal_load(inv_idx4 + t);
    const iv4 si = __builtin_nontemporal_load(src_idx4 + t);
    const iv4 ti = __builtin_nontemporal_load(tgt_idx4 + t);

    const fv4 bl01 = __builtin_nontemporal_load(baseline4 + 2 * t);
    const fv4 bl23 = __builtin_nontemporal_load(baseline4 + 2 * t + 1);
    const fv4 w01  = __builtin_nontemporal_load(weights4 + 2 * t);
    const fv4 w23  = __builtin_nontemporal_load(weights4 + 2 * t + 1);

    float rx[4], ry[4];
#pragma unroll
    for (int i = 0; i < 4; ++i) {
        const int p = ((const int*)&pi)[i];
        const int v = ((const int*)&ii)[i];
        const int s = ((const int*)&si)[i];
        const int g = ((const int*)&ti)[i];
        const float r  = pc_rt[2 * (size_t)p];
        const float th = pc_rt[2 * (size_t)p + 1];
        const float phi = elev[v];
        const float* Pp = poses + (size_t)s * 7;
        const float* Tp = poses + (size_t)g * 7;

        float sphi, cphi, sth, cth;
        __sincosf(phi, &sphi, &cphi);
        __sincosf(th,  &sth,  &cth);
        const float rcp = r * cphi;
        const float lx = rcp * cth, ly = rcp * sth, lz = r * sphi;

        const float qx = Pp[3], qy = Pp[4], qz = Pp[5], qw = Pp[6];
        const float t0 = 2.0f * (qy * lz - qz * ly);
        const float t1 = 2.0f * (qz * lx - qx * lz);
        const float t2 = 2.0f * (qx * ly - qy * lx);
        const float gx = lx + qw * t0 + (qy * t2 - qz * t1) + Pp[0];
        const float gy = ly + qw * t1 + (qz * t0 - qx * t2) + Pp[1];
        const float gz = lz + qw * t2 + (qx * t1 - qy * t0) + Pp[2];

        const float dx = gx - Tp[0], dy = gy - Tp[1], dz = gz - Tp[2];
        const float uqx = -Tp[3], uqy = -Tp[4], uqz = -Tp[5], uqw = Tp[6];
        const float u0 = 2.0f * (uqy * dz - uqz * dy);
        const float u1 = 2.0f * (uqz * dx - uqx * dz);
        const float u2 = 2.0f * (uqx * dy - uqy * dx);
        const float ox = dx + uqw * u0 + (uqy * u2 - uqz * u1);
        const float oy = dy + uqw * u1 + (uqz * u0 - uqx * u2);
        const float oz = dz + uqw * u2 + (uqx * u1 - uqy * u0);

        rx[i] = sqrtf(ox * ox + oy * oy + oz * oz) * sx;
        ry[i] = atan2f(oy, ox) * sy;
    }

    fv4 o01, o23;
    o01.x = (rx[0] - bl01.x) * sqrtf(w01.x + EPS_W);
    o01.y = (ry[0] - bl01.y) * sqrtf(w01.y + EPS_W);
    o01.z = (rx[1] - bl01.z) * sqrtf(w01.z + EPS_W);
    o01.w = (ry[1] - bl01.w) * sqrtf(w01.w + EPS_W);
    o23.x = (rx[2] - bl23.x) * sqrtf(w23.x + EPS_W);
    o23.y = (ry[2] - bl23.y) * sqrtf(w23.y + EPS_W);
    o23.z = (rx[3] - bl23.z) * sqrtf(w23.z + EPS_W);
    o23.w = (ry[3] - bl23.w) * sqrtf(w23.w + EPS_W);

    __builtin_nontemporal_store(o01, out4 + 2 * t);
    __builtin_nontemporal_store(o23, out4 + 2 * t + 1);
}

extern "C" void kernel_launch(void* const* d_in, const int* in_sizes, int n_in,
                              void* d_out, int out_size, void* d_ws, size_t ws_size,
                              hipStream_t stream) {
    const float* poses    = (const float*)d_in[0];
    const float* pc_rt    = (const float*)d_in[1];
    const float* elev     = (const float*)d_in[2];
    const float* scale    = (const float*)d_in[3];
    const fv4*   baseline = (const fv4*)d_in[4];
    const fv4*   weights4 = (const fv4*)d_in[5];
    const iv4*   patch_i  = (const iv4*)d_in[6];
    const iv4*   inv_i    = (const iv4*)d_in[7];
    const iv4*   src_i    = (const iv4*)d_in[8];
    const iv4*   tgt_i    = (const iv4*)d_in[9];
    fv4*         out      = (fv4*)d_out;

    const size_t local4_bytes = (size_t)N_PATCH * 16;
    const size_t poses8_bytes = (size_t)N_POSES * 32;
    const int threads = E_EDGES / 4;  // 1,048,576

    if (ws_size >= local4_bytes + poses8_bytes) {
        fv4* local4 = (fv4*)d_ws;
        fv4* poses8 = (fv4*)((char*)d_ws + local4_bytes);

        hipLaunchKernelGGL(prep_patches, dim3(N_PATCH / 256), dim3(256), 0, stream,
                           (const fv2*)pc_rt, elev, local4);
        hipLaunchKernelGGL(prep_poses, dim3(N_POSES / 256), dim3(256), 0, stream,
                           poses, poses8);
        hipLaunchKernelGGL(ba_main, dim3(threads / 256), dim3(256), 0, stream,
                           (const fv4*)poses8, (const fv4*)local4, scale,
                           baseline, weights4, patch_i, src_i, tgt_i, out);
    } else {
        hipLaunchKernelGGL(ba_fallback, dim3(threads / 256), dim3(256), 0, stream,
                           poses, pc_rt, elev, scale, baseline, weights4,
                           patch_i, inv_i, src_i, tgt_i, out);
    }
}